// Round 1
// baseline (521.436 us; speedup 1.0000x reference)
//
#include <hip/hip_runtime.h>
#include <stdint.h>

typedef __bf16 bf16_t;
typedef __bf16 bf16x8 __attribute__((ext_vector_type(8)));
typedef __bf16 bf16x4 __attribute__((ext_vector_type(4)));
typedef float  f32x4  __attribute__((ext_vector_type(4)));

union U16x8 { uint2 u[2]; bf16x8 v; };

// ---------------- f32 -> bf16 convert (vectorized) ----------------
__global__ void k_convert_bf16(const float* __restrict__ in, bf16_t* __restrict__ out, int n4)
{
    int i = blockIdx.x * blockDim.x + threadIdx.x;
    const int stride = gridDim.x * blockDim.x;
    for (; i < n4; i += stride) {
        float4 v = ((const float4*)in)[i];
        bf16x4 o;
        o[0] = (bf16_t)v.x; o[1] = (bf16_t)v.y; o[2] = (bf16_t)v.z; o[3] = (bf16_t)v.w;
        ((bf16x4*)out)[i] = o;
    }
}

// ---------------- transpose f32 [R][C] -> bf16 [C][R] ----------------
__global__ void k_transpose_bf16(const float* __restrict__ in, bf16_t* __restrict__ out, int R, int C)
{
    __shared__ float tile[32][33];
    const int c0 = blockIdx.x * 32, r0 = blockIdx.y * 32;
    const int tid = threadIdx.x;
    const int c = tid & 31, r = tid >> 5;
#pragma unroll
    for (int i = 0; i < 4; ++i)
        tile[r + i * 8][c] = in[(size_t)(r0 + r + i * 8) * C + (c0 + c)];
    __syncthreads();
#pragma unroll
    for (int i = 0; i < 4; ++i)
        out[(size_t)(c0 + r + i * 8) * R + (r0 + c)] = (bf16_t)tile[c][r + i * 8];
}

// ---------------- GEMM: C[M][N] = A[M][K] * Bt[N][K]^T + bias ----------------
// MODE 0: qkv split-writer (q,k row-major bf16; v transposed to [B][D][N] bf16)
// MODE 1: f32 out + bias (proj)
// LDS tiles hold swizzled rows: LDS[r][cb] = global[r][cb ^ ((r&7)<<4)] (byte addressing)
template<int MODE>
__global__ __launch_bounds__(256, 2)
void gemm_bt(const bf16_t* __restrict__ A, const bf16_t* __restrict__ Bt,
             const float* __restrict__ bias,
             void* __restrict__ out0, void* __restrict__ out1, void* __restrict__ out2,
             int Mtot, int Nn, int K)
{
    __shared__ bf16_t As[128 * 64];
    __shared__ bf16_t Bs[128 * 64];
    const int tid = threadIdx.x;
    const int lane = tid & 63;
    const int w = tid >> 6;
    const int wm = w >> 1, wn = w & 1;
    const int lm = lane & 15, g = lane >> 4;
    const int row0 = blockIdx.y * 128, col0 = blockIdx.x * 128;

    f32x4 acc[4][4];
#pragma unroll
    for (int i = 0; i < 4; ++i)
#pragma unroll
        for (int j = 0; j < 4; ++j) {
            acc[i][j][0] = 0.f; acc[i][j][1] = 0.f; acc[i][j][2] = 0.f; acc[i][j][3] = 0.f;
        }

    const int nkb = K >> 6;
    for (int kb = 0; kb < nkb; ++kb) {
        uint4 ra[4], rb[4];
#pragma unroll
        for (int it = 0; it < 4; ++it) {
            int blk = it * 256 + tid;       // 0..1023 : 16B blocks of the 128x64 tile
            int r = blk >> 3;               // tile row
            int cb = (blk & 7) << 4;        // byte within row
            int sb = cb ^ ((r & 7) << 4);   // pre-swizzled global source byte
            ra[it] = *(const uint4*)((const char*)(A  + (size_t)(row0 + r) * K + kb * 64) + sb);
            rb[it] = *(const uint4*)((const char*)(Bt + (size_t)(col0 + r) * K + kb * 64) + sb);
        }
        __syncthreads();  // previous compute done reading LDS
#pragma unroll
        for (int it = 0; it < 4; ++it) {
            int blk = it * 256 + tid;
            *(uint4*)((char*)As + blk * 16) = ra[it];
            *(uint4*)((char*)Bs + blk * 16) = rb[it];
        }
        __syncthreads();  // tiles ready
#pragma unroll
        for (int kk = 0; kk < 2; ++kk) {
            bf16x8 af[4], bfr[4];
#pragma unroll
            for (int f = 0; f < 4; ++f) {
                {
                    int r = wm * 64 + f * 16 + lm;
                    int sw = (r & 7) << 4;
                    int c0b = kk * 64 + g * 8;
                    U16x8 u;
                    u.u[0] = *(const uint2*)((const char*)As + r * 128 + (c0b ^ sw));
                    u.u[1] = *(const uint2*)((const char*)As + r * 128 + ((c0b + 32) ^ sw));
                    af[f] = u.v;
                }
                {
                    int r = wn * 64 + f * 16 + lm;
                    int sw = (r & 7) << 4;
                    int c0b = kk * 64 + g * 8;
                    U16x8 u;
                    u.u[0] = *(const uint2*)((const char*)Bs + r * 128 + (c0b ^ sw));
                    u.u[1] = *(const uint2*)((const char*)Bs + r * 128 + ((c0b + 32) ^ sw));
                    bfr[f] = u.v;
                }
            }
#pragma unroll
            for (int i = 0; i < 4; ++i)
#pragma unroll
                for (int j = 0; j < 4; ++j)
                    acc[i][j] = __builtin_amdgcn_mfma_f32_16x16x32_bf16(af[i], bfr[j], acc[i][j], 0, 0, 0);
        }
    }

    // epilogue: C col = lane&15, row = 4*(lane>>4)+reg  [HW-verified layout]
    if constexpr (MODE == 0) {
        bf16_t* qo = (bf16_t*)out0;
        bf16_t* ko = (bf16_t*)out1;
        bf16_t* vo = (bf16_t*)out2;
#pragma unroll
        for (int j = 0; j < 4; ++j) {
            int ncol = col0 + wn * 64 + j * 16 + lm;
            float bv = bias[ncol];
#pragma unroll
            for (int i = 0; i < 4; ++i) {
                int rbase = row0 + wm * 64 + i * 16 + g * 4;
                if (ncol < 1024) {
#pragma unroll
                    for (int r = 0; r < 4; ++r)
                        qo[(size_t)(rbase + r) * 1024 + ncol] = (bf16_t)(acc[i][j][r] + bv);
                } else if (ncol < 2048) {
                    int c = ncol - 1024;
#pragma unroll
                    for (int r = 0; r < 4; ++r)
                        ko[(size_t)(rbase + r) * 1024 + c] = (bf16_t)(acc[i][j][r] + bv);
                } else {
                    int d = ncol - 2048;
                    int bb = rbase >> 11;      // batch (N=2048 rows per batch)
                    int n = rbase & 2047;
                    bf16x4 pk;
#pragma unroll
                    for (int r = 0; r < 4; ++r) pk[r] = (bf16_t)(acc[i][j][r] + bv);
                    *(bf16x4*)(vo + (size_t)bb * 1024 * 2048 + (size_t)d * 2048 + n) = pk;
                }
            }
        }
    } else {
        float* oo = (float*)out0;
#pragma unroll
        for (int j = 0; j < 4; ++j) {
            int ncol = col0 + wn * 64 + j * 16 + lm;
            float bv = bias[ncol];
#pragma unroll
            for (int i = 0; i < 4; ++i) {
                int rbase = row0 + wm * 64 + i * 16 + g * 4;
#pragma unroll
                for (int r = 0; r < 4; ++r)
                    oo[(size_t)(rbase + r) * Nn + ncol] = acc[i][j][r] + bv;
            }
        }
    }
}

// ---------------- local attention ----------------
// 32 queries per block, 4 waves. Fixed 288-key strip [jlo, jlo+288), window mask per element.
// Q[BN][D], K[BN][D] row-major bf16; V pre-transposed: Vt[B][D][N] bf16.
__global__ __launch_bounds__(256, 1)
void k_attn(const bf16_t* __restrict__ Q, const bf16_t* __restrict__ Km,
            const bf16_t* __restrict__ Vt, bf16_t* __restrict__ AO,
            const int* __restrict__ wptr)
{
    constexpr int Nn = 2048, Dd = 1024;
    constexpr int NJT = 18, JROWS = 288;
    __shared__ bf16_t Qs[32][1032];       // +8 pad -> conflict-free frag reads
    __shared__ bf16_t Ks[16][1032];
    __shared__ float  St[JROWS][33];      // scores, later p=exp(s-m)
    __shared__ float  Spart[4][16][36];   // per-wave partial scores (stored [j][q])
    __shared__ float  red[8][32];
    __shared__ float  rowrsum[32];

    const int tid = threadIdx.x;
    const int lane = tid & 63;
    const int w = tid >> 6;
    const int lm = lane & 15, g = lane >> 4;
    const int blk = blockIdx.x;
    const int b = blk >> 6;
    const int q0 = (blk & 63) * 32;
    const int win = *wptr;
    int jlo = q0 - win; if (jlo < 0) jlo = 0;

    // stage Q tile (32 x 1024 bf16)
    {
        const bf16_t* src = Q + ((size_t)(b * Nn + q0)) * Dd;
#pragma unroll
        for (int i = 0; i < 16; ++i) {
            int b16 = i * 256 + tid;
            int r = b16 >> 7;
            int ce = (b16 & 127) * 8;
            uint4 v = *(const uint4*)(src + (size_t)r * Dd + ce);
            *(uint4*)(&Qs[r][ce]) = v;
        }
    }

    // score strip: per 16-key tile, waves split the D-reduction
    for (int jt = 0; jt < NJT; ++jt) {
        __syncthreads();
#pragma unroll
        for (int i = 0; i < 8; ++i) {
            int b16 = i * 256 + tid;
            int r = b16 >> 7;
            int ce = (b16 & 127) * 8;
            int jg = jlo + jt * 16 + r;
            uint4 v = make_uint4(0u, 0u, 0u, 0u);
            if (jg < Nn) v = *(const uint4*)(Km + ((size_t)(b * Nn + jg)) * Dd + ce);
            *(uint4*)(&Ks[r][ce]) = v;
        }
        __syncthreads();
        f32x4 sacc[2];
#pragma unroll
        for (int f = 0; f < 2; ++f) { sacc[f][0]=0.f; sacc[f][1]=0.f; sacc[f][2]=0.f; sacc[f][3]=0.f; }
#pragma unroll
        for (int ks = 0; ks < 8; ++ks) {
            int d0 = w * 256 + ks * 32;
            U16x8 kf;
            kf.u[0] = *(const uint2*)(&Ks[lm][d0 + g * 4]);
            kf.u[1] = *(const uint2*)(&Ks[lm][d0 + 16 + g * 4]);
#pragma unroll
            for (int f = 0; f < 2; ++f) {
                U16x8 qf;
                qf.u[0] = *(const uint2*)(&Qs[f * 16 + lm][d0 + g * 4]);
                qf.u[1] = *(const uint2*)(&Qs[f * 16 + lm][d0 + 16 + g * 4]);
                sacc[f] = __builtin_amdgcn_mfma_f32_16x16x32_bf16(qf.v, kf.v, sacc[f], 0, 0, 0);
            }
        }
        // C layout: col=lane&15 -> j=lm ; row=4*(lane>>4)+r -> q=f*16+4g+r
#pragma unroll
        for (int f = 0; f < 2; ++f)
            *(f32x4*)(&Spart[w][lm][f * 16 + g * 4]) = sacc[f];
        __syncthreads();
        {
            int j = tid >> 4;
            int q2 = (tid & 15) * 2;
#pragma unroll
            for (int t = 0; t < 2; ++t) {
                int qq = q2 + t;
                float s = Spart[0][j][qq] + Spart[1][j][qq] + Spart[2][j][qq] + Spart[3][j][qq];
                s *= 0.03125f;  // D^-0.5
                int jg = jlo + jt * 16 + j;
                int qg = q0 + qq;
                int dd = qg - jg; if (dd < 0) dd = -dd;
                bool valid = (jg < Nn) && (dd <= win);
                St[jt * 16 + j][qq] = valid ? s : -3.0e38f;
            }
        }
    }
    __syncthreads();

    // softmax over j, per q column; 8 threads per q
    {
        int qq = tid & 31, sub = tid >> 5;
        float m = -3.0e38f;
        for (int j = sub; j < JROWS; j += 8) m = fmaxf(m, St[j][qq]);
        red[sub][qq] = m;
        __syncthreads();
        float mm = red[0][qq];
#pragma unroll
        for (int s2 = 1; s2 < 8; ++s2) mm = fmaxf(mm, red[s2][qq]);
        __syncthreads();   // all reads of red done before re-use
        float sum = 0.f;
        for (int j = sub; j < JROWS; j += 8) {
            float p = __expf(St[j][qq] - mm);
            St[j][qq] = p;
            sum += p;
        }
        red[sub][qq] = sum;
        __syncthreads();
        float ss = 0.f;
#pragma unroll
        for (int s2 = 0; s2 < 8; ++s2) ss += red[s2][qq];
        if (sub == 0) rowrsum[qq] = 1.f / ss;
    }
    __syncthreads();

    // PV: wave w owns output d-chunk [w*256, w*256+256)
    f32x4 oacc[2][16];
#pragma unroll
    for (int f = 0; f < 2; ++f)
#pragma unroll
        for (int nf = 0; nf < 16; ++nf) { oacc[f][nf][0]=0.f; oacc[f][nf][1]=0.f; oacc[f][nf][2]=0.f; oacc[f][nf][3]=0.f; }

    const bf16_t* vbase = Vt + (size_t)b * Dd * Nn;
#pragma unroll 1
    for (int ks = 0; ks < 9; ++ks) {   // 288/32
        int jb = ks * 32;
        bf16x8 pf[2];
#pragma unroll
        for (int f = 0; f < 2; ++f) {
            int qq = f * 16 + lm;
            bf16x8 v;
#pragma unroll
            for (int h = 0; h < 2; ++h)
#pragma unroll
                for (int i2 = 0; i2 < 4; ++i2)
                    v[h * 4 + i2] = (bf16_t)St[jb + h * 16 + g * 4 + i2][qq];
            pf[f] = v;
        }
        U16x8 bl[16];
        int j0g = jlo + jb + g * 4;      if (j0g > Nn - 4) j0g = Nn - 4;   // clamped lanes have p=0
        int j1g = jlo + jb + 16 + g * 4; if (j1g > Nn - 4) j1g = Nn - 4;
#pragma unroll
        for (int nf = 0; nf < 16; ++nf) {
            int d = w * 256 + nf * 16 + lm;
            const bf16_t* vp = vbase + (size_t)d * Nn;
            bl[nf].u[0] = *(const uint2*)(vp + j0g);
            bl[nf].u[1] = *(const uint2*)(vp + j1g);
        }
#pragma unroll
        for (int nf = 0; nf < 16; ++nf)
#pragma unroll
            for (int f = 0; f < 2; ++f)
                oacc[f][nf] = __builtin_amdgcn_mfma_f32_16x16x32_bf16(pf[f], bl[nf].v, oacc[f][nf], 0, 0, 0);
    }

    // epilogue: scale by 1/sum, write bf16
#pragma unroll
    for (int f = 0; f < 2; ++f) {
#pragma unroll
        for (int r = 0; r < 4; ++r) {
            int qq = f * 16 + g * 4 + r;
            float rs = rowrsum[qq];
            size_t rowg = (size_t)(b * Nn + q0 + qq) * Dd;
#pragma unroll
            for (int nf = 0; nf < 16; ++nf) {
                int d = w * 256 + nf * 16 + lm;
                AO[rowg + d] = (bf16_t)(oacc[f][nf][r] * rs);
            }
        }
    }
}

extern "C" void kernel_launch(void* const* d_in, const int* in_sizes, int n_in,
                              void* d_out, int out_size, void* d_ws, size_t ws_size,
                              hipStream_t stream)
{
    (void)in_sizes; (void)n_in; (void)out_size; (void)ws_size;
    const float* x      = (const float*)d_in[0];
    const float* w_qkv  = (const float*)d_in[1];
    const float* b_qkv  = (const float*)d_in[2];
    const float* w_proj = (const float*)d_in[3];
    const float* b_proj = (const float*)d_in[4];
    const int*   wsz    = (const int*)d_in[5];
    float* out = (float*)d_out;

    constexpr int Bb = 4, Nn = 2048, Dd = 1024;
    constexpr int M = Bb * Nn, N3 = 3 * Dd;

    char* p = (char*)d_ws;
    bf16_t* xb     = (bf16_t*)p; p += (size_t)M * Dd * 2;    // also reused as attn-out
    bf16_t* wqkvT  = (bf16_t*)p; p += (size_t)N3 * Dd * 2;
    bf16_t* wprojT = (bf16_t*)p; p += (size_t)Dd * Dd * 2;
    bf16_t* qb     = (bf16_t*)p; p += (size_t)M * Dd * 2;
    bf16_t* kb     = (bf16_t*)p; p += (size_t)M * Dd * 2;
    bf16_t* vtb    = (bf16_t*)p; p += (size_t)M * Dd * 2;
    bf16_t* ao     = xb;  // alias: xb dead after QKV GEMM

    k_convert_bf16<<<2048, 256, 0, stream>>>(x, xb, M * Dd / 4);
    k_transpose_bf16<<<dim3(N3 / 32, Dd / 32), 256, 0, stream>>>(w_qkv, wqkvT, Dd, N3);
    k_transpose_bf16<<<dim3(Dd / 32, Dd / 32), 256, 0, stream>>>(w_proj, wprojT, Dd, Dd);
    gemm_bt<0><<<dim3(N3 / 128, M / 128), 256, 0, stream>>>(xb, wqkvT, b_qkv, qb, kb, vtb, M, N3, Dd);
    k_attn<<<Bb * (Nn / 32), 256, 0, stream>>>(qb, kb, vtb, ao, wsz);
    gemm_bt<1><<<dim3(Dd / 128, M / 128), 256, 0, stream>>>(ao, wprojT, b_proj, out, nullptr, nullptr, M, Dd, Dd);
}

// Round 8
// 296.637 us; speedup vs baseline: 1.7578x; 1.7578x over previous
//
#include <hip/hip_runtime.h>
#include <stdint.h>

typedef __bf16 bf16_t;
typedef __bf16 bf16x8 __attribute__((ext_vector_type(8)));
typedef __bf16 bf16x4 __attribute__((ext_vector_type(4)));
typedef float  f32x4  __attribute__((ext_vector_type(4)));

union U16x8 { uint2 u[2]; bf16x8 v; };

// async global->LDS, 16B per lane. LDS dest must be wave-uniform-base + lane*16.
__device__ __forceinline__ void gl_lds16(const void* g, void* l)
{
#if __has_builtin(__builtin_amdgcn_global_load_lds)
    __builtin_amdgcn_global_load_lds(
        (const __attribute__((address_space(1))) unsigned int*)g,
        (__attribute__((address_space(3))) unsigned int*)l, 16, 0, 0);
#else
    *(uint4*)l = *(const uint4*)g;
#endif
}

// ---------------- f32 -> bf16 convert (vectorized) ----------------
__global__ void k_convert_bf16(const float* __restrict__ in, bf16_t* __restrict__ out, int n4)
{
    int i = blockIdx.x * blockDim.x + threadIdx.x;
    const int stride = gridDim.x * blockDim.x;
    for (; i < n4; i += stride) {
        float4 v = ((const float4*)in)[i];
        bf16x4 o;
        o[0] = (bf16_t)v.x; o[1] = (bf16_t)v.y; o[2] = (bf16_t)v.z; o[3] = (bf16_t)v.w;
        ((bf16x4*)out)[i] = o;
    }
}

// ---------------- transpose f32 [R][C] -> bf16 [C][R] ----------------
__global__ void k_transpose_bf16(const float* __restrict__ in, bf16_t* __restrict__ out, int R, int C)
{
    __shared__ float tile[32][33];
    const int c0 = blockIdx.x * 32, r0 = blockIdx.y * 32;
    const int tid = threadIdx.x;
    const int c = tid & 31, r = tid >> 5;
#pragma unroll
    for (int i = 0; i < 4; ++i)
        tile[r + i * 8][c] = in[(size_t)(r0 + r + i * 8) * C + (c0 + c)];
    __syncthreads();
#pragma unroll
    for (int i = 0; i < 4; ++i)
        out[(size_t)(c0 + r + i * 8) * R + (r0 + c)] = (bf16_t)tile[c][r + i * 8];
}

// ---------------- GEMM: C[M][N] = A[M][K] * Bt[N][K]^T + bias ----------------
// MODE 0: qkv split-writer (q,k row-major bf16; v transposed to [B][D][N] bf16)
// MODE 1: f32 out + bias (proj) — direct stores are already full-64B-line coalesced
// Staging: global_load_lds w=16, LINEAR LDS dest, pre-swizzled global source
// (byte XOR (r&7)<<4 within the 128B row), swizzled ds_read on consume.
template<int MODE>
__global__ __launch_bounds__(256, 2)
void gemm_bt(const bf16_t* __restrict__ A, const bf16_t* __restrict__ Bt,
             const float* __restrict__ bias,
             void* __restrict__ out0, void* __restrict__ out1, void* __restrict__ out2,
             int nbx, int Nn, int K)
{
    __shared__ __align__(16) char smem[34816];   // As 16K + Bs 16K; epilogue: 128x136 bf16 tile
    bf16_t* As = (bf16_t*)smem;
    bf16_t* Bs = (bf16_t*)(smem + 16384);

    const int tid = threadIdx.x;
    const int lane = tid & 63;
    const int w = tid >> 6;
    const int wm = w >> 1, wn = w & 1;
    const int lm = lane & 15, g = lane >> 4;

    // bijective XCD swizzle (gridDim.x % 8 == 0 for both instantiations)
    const int nwg = gridDim.x;
    const int bid = (blockIdx.x & 7) * (nwg >> 3) + (blockIdx.x >> 3);
    const int bx = bid % nbx, by = bid / nbx;
    const int row0 = by * 128, col0 = bx * 128;

    f32x4 acc[4][4];
#pragma unroll
    for (int i = 0; i < 4; ++i)
#pragma unroll
        for (int j = 0; j < 4; ++j) {
            acc[i][j][0] = 0.f; acc[i][j][1] = 0.f; acc[i][j][2] = 0.f; acc[i][j][3] = 0.f;
        }

    const int nkb = K >> 6;
    for (int kb = 0; kb < nkb; ++kb) {
#pragma unroll
        for (int it = 0; it < 4; ++it) {
            int blk = it * 256 + tid;       // 16B chunk index of the 128x64 tile
            int r = blk >> 3;               // tile row
            int cb = (blk & 7) << 4;        // byte within row (linear LDS dest)
            int sb = cb ^ ((r & 7) << 4);   // pre-swizzled global source byte
            gl_lds16((const char*)(A  + (size_t)(row0 + r) * K + kb * 64) + sb, (char*)As + blk * 16);
            gl_lds16((const char*)(Bt + (size_t)(col0 + r) * K + kb * 64) + sb, (char*)Bs + blk * 16);
        }
        __syncthreads();   // drains vmcnt(0) -> tiles ready
#pragma unroll
        for (int kk = 0; kk < 2; ++kk) {
            bf16x8 af[4], bfr[4];
#pragma unroll
            for (int f = 0; f < 4; ++f) {
                int ra = wm * 64 + f * 16 + lm;
                int swa = (ra & 7) << 4;
                int c0b = kk * 64 + g * 8;
                U16x8 u;
                u.u[0] = *(const uint2*)((const char*)As + ra * 128 + (c0b ^ swa));
                u.u[1] = *(const uint2*)((const char*)As + ra * 128 + ((c0b + 32) ^ swa));
                af[f] = u.v;
                int rb = wn * 64 + f * 16 + lm;
                int swb = (rb & 7) << 4;
                U16x8 ub;
                ub.u[0] = *(const uint2*)((const char*)Bs + rb * 128 + (c0b ^ swb));
                ub.u[1] = *(const uint2*)((const char*)Bs + rb * 128 + ((c0b + 32) ^ swb));
                bfr[f] = ub.v;
            }
#pragma unroll
            for (int i = 0; i < 4; ++i)
#pragma unroll
                for (int j = 0; j < 4; ++j)
                    acc[i][j] = __builtin_amdgcn_mfma_f32_16x16x32_bf16(af[i], bfr[j], acc[i][j], 0, 0, 0);
        }
        __syncthreads();   // compute done before next tile overwrites LDS
    }

    // ---- epilogue: C col = lane&15, row = 4*(lane>>4)+reg [HW-verified] ----
    if constexpr (MODE == 1) {
        float* oo = (float*)out0;
#pragma unroll
        for (int j = 0; j < 4; ++j) {
            int ncol = col0 + wn * 64 + j * 16 + lm;
            float bv = bias[ncol];
#pragma unroll
            for (int i = 0; i < 4; ++i) {
                int rbase = row0 + wm * 64 + i * 16 + g * 4;
#pragma unroll
                for (int r = 0; r < 4; ++r)
                    oo[(size_t)(rbase + r) * Nn + ncol] = acc[i][j][r] + bv;
            }
        }
    } else {
        bf16_t* tile = (bf16_t*)smem;      // [128][136] bf16 (pad keeps 16B row align)
        constexpr int TP = 136;
        const int region = col0 >> 10;     // 0=q, 1=k, 2=v (block never straddles)
        if (region < 2) {
            // row-major restage -> coalesced 16B/lane stores
#pragma unroll
            for (int j = 0; j < 4; ++j) {
                int cl = wn * 64 + j * 16 + lm;
                float bv = bias[col0 + cl];
#pragma unroll
                for (int i = 0; i < 4; ++i) {
                    int rl = wm * 64 + i * 16 + g * 4;
#pragma unroll
                    for (int r = 0; r < 4; ++r)
                        tile[(rl + r) * TP + cl] = (bf16_t)(acc[i][j][r] + bv);
                }
            }
            __syncthreads();
            bf16_t* dst = (region == 0) ? (bf16_t*)out0 : (bf16_t*)out1;
            const int colbase = col0 & 1023;
            // full tile = 128 rows x 16 chunks of 8 bf16 = 2048 chunks -> 8 iters x 256 threads
#pragma unroll
            for (int it = 0; it < 8; ++it) {
                int blk = it * 256 + tid;
                int rr = blk >> 4;
                int c8 = (blk & 15) * 8;
                uint4 v = *(const uint4*)&tile[rr * TP + c8];
                *(uint4*)(dst + (size_t)(row0 + rr) * 1024 + colbase + c8) = v;
            }
        } else {
            // v: transposed restage (tileT[col][row]) -> coalesced [B][D][N] stores
#pragma unroll
            for (int j = 0; j < 4; ++j) {
                int cl = wn * 64 + j * 16 + lm;
                float bv = bias[col0 + cl];
#pragma unroll
                for (int i = 0; i < 4; ++i) {
                    int rl = wm * 64 + i * 16 + g * 4;
                    bf16x4 pk;
#pragma unroll
                    for (int r = 0; r < 4; ++r) pk[r] = (bf16_t)(acc[i][j][r] + bv);
                    *(bf16x4*)&tile[cl * TP + rl] = pk;     // 8B, aligned
                }
            }
            __syncthreads();
            bf16_t* vo = (bf16_t*)out2;
            const int bb = row0 >> 11;         // batch (2048 rows per batch; block never straddles)
            const int n0 = row0 & 2047;
            const int dbase = col0 - 2048;
#pragma unroll
            for (int it = 0; it < 8; ++it) {
                int blk = it * 256 + tid;
                int dl = blk >> 4;
                int n8 = (blk & 15) * 8;
                uint4 v = *(const uint4*)&tile[dl * TP + n8];
                *(uint4*)(vo + (size_t)bb * (1024 * 2048) + (size_t)(dbase + dl) * 2048 + (n0 + n8)) = v;
            }
        }
    }
}

// ---------------- local attention ----------------
// 32 queries per block, 4 waves. Fixed 288-key strip [jlo, jlo+288), window mask per element.
// Q[BN][D], K[BN][D] row-major bf16; V pre-transposed: Vt[B][D][N] bf16.
__global__ __launch_bounds__(256, 1)
void k_attn(const bf16_t* __restrict__ Q, const bf16_t* __restrict__ Km,
            const bf16_t* __restrict__ Vt, bf16_t* __restrict__ AO,
            const int* __restrict__ wptr)
{
    constexpr int Nn = 2048, Dd = 1024;
    constexpr int NJT = 18, JROWS = 288;
    __shared__ bf16_t Qs[32][1032];
    __shared__ bf16_t Ks[16][1032];
    __shared__ float  St[JROWS][33];
    __shared__ float  Spart[4][16][36];
    __shared__ float  red[8][32];
    __shared__ float  rowrsum[32];

    const int tid = threadIdx.x;
    const int lane = tid & 63;
    const int w = tid >> 6;
    const int lm = lane & 15, g = lane >> 4;
    const int blk = blockIdx.x;
    const int b = blk >> 6;
    const int q0 = (blk & 63) * 32;
    const int win = *wptr;
    int jlo = q0 - win; if (jlo < 0) jlo = 0;

    {
        const bf16_t* src = Q + ((size_t)(b * Nn + q0)) * Dd;
#pragma unroll
        for (int i = 0; i < 16; ++i) {
            int b16 = i * 256 + tid;
            int r = b16 >> 7;
            int ce = (b16 & 127) * 8;
            uint4 v = *(const uint4*)(src + (size_t)r * Dd + ce);
            *(uint4*)(&Qs[r][ce]) = v;
        }
    }

    for (int jt = 0; jt < NJT; ++jt) {
        __syncthreads();
#pragma unroll
        for (int i = 0; i < 8; ++i) {
            int b16 = i * 256 + tid;
            int r = b16 >> 7;
            int ce = (b16 & 127) * 8;
            int jg = jlo + jt * 16 + r;
            uint4 v = make_uint4(0u, 0u, 0u, 0u);
            if (jg < Nn) v = *(const uint4*)(Km + ((size_t)(b * Nn + jg)) * Dd + ce);
            *(uint4*)(&Ks[r][ce]) = v;
        }
        __syncthreads();
        f32x4 sacc[2];
#pragma unroll
        for (int f = 0; f < 2; ++f) { sacc[f][0]=0.f; sacc[f][1]=0.f; sacc[f][2]=0.f; sacc[f][3]=0.f; }
#pragma unroll
        for (int ks = 0; ks < 8; ++ks) {
            int d0 = w * 256 + ks * 32;
            U16x8 kf;
            kf.u[0] = *(const uint2*)(&Ks[lm][d0 + g * 4]);
            kf.u[1] = *(const uint2*)(&Ks[lm][d0 + 16 + g * 4]);
#pragma unroll
            for (int f = 0; f < 2; ++f) {
                U16x8 qf;
                qf.u[0] = *(const uint2*)(&Qs[f * 16 + lm][d0 + g * 4]);
                qf.u[1] = *(const uint2*)(&Qs[f * 16 + lm][d0 + 16 + g * 4]);
                sacc[f] = __builtin_amdgcn_mfma_f32_16x16x32_bf16(qf.v, kf.v, sacc[f], 0, 0, 0);
            }
        }
#pragma unroll
        for (int f = 0; f < 2; ++f)
            *(f32x4*)(&Spart[w][lm][f * 16 + g * 4]) = sacc[f];
        __syncthreads();
        {
            int j = tid >> 4;
            int q2 = (tid & 15) * 2;
#pragma unroll
            for (int t = 0; t < 2; ++t) {
                int qq = q2 + t;
                float s = Spart[0][j][qq] + Spart[1][j][qq] + Spart[2][j][qq] + Spart[3][j][qq];
                s *= 0.03125f;
                int jg = jlo + jt * 16 + j;
                int qg = q0 + qq;
                int dd = qg - jg; if (dd < 0) dd = -dd;
                bool valid = (jg < Nn) && (dd <= win);
                St[jt * 16 + j][qq] = valid ? s : -3.0e38f;
            }
        }
    }
    __syncthreads();

    {
        int qq = tid & 31, sub = tid >> 5;
        float m = -3.0e38f;
        for (int j = sub; j < JROWS; j += 8) m = fmaxf(m, St[j][qq]);
        red[sub][qq] = m;
        __syncthreads();
        float mm = red[0][qq];
#pragma unroll
        for (int s2 = 1; s2 < 8; ++s2) mm = fmaxf(mm, red[s2][qq]);
        __syncthreads();
        float sum = 0.f;
        for (int j = sub; j < JROWS; j += 8) {
            float p = __expf(St[j][qq] - mm);
            St[j][qq] = p;
            sum += p;
        }
        red[sub][qq] = sum;
        __syncthreads();
        float ss = 0.f;
#pragma unroll
        for (int s2 = 0; s2 < 8; ++s2) ss += red[s2][qq];
        if (sub == 0) rowrsum[qq] = 1.f / ss;
    }
    __syncthreads();

    f32x4 oacc[2][16];
#pragma unroll
    for (int f = 0; f < 2; ++f)
#pragma unroll
        for (int nf = 0; nf < 16; ++nf) { oacc[f][nf][0]=0.f; oacc[f][nf][1]=0.f; oacc[f][nf][2]=0.f; oacc[f][nf][3]=0.f; }

    const bf16_t* vbase = Vt + (size_t)b * Dd * Nn;
#pragma unroll 1
    for (int ks = 0; ks < 9; ++ks) {
        int jb = ks * 32;
        bf16x8 pf[2];
#pragma unroll
        for (int f = 0; f < 2; ++f) {
            int qq = f * 16 + lm;
            bf16x8 v;
#pragma unroll
            for (int h = 0; h < 2; ++h)
#pragma unroll
                for (int i2 = 0; i2 < 4; ++i2)
                    v[h * 4 + i2] = (bf16_t)St[jb + h * 16 + g * 4 + i2][qq];
            pf[f] = v;
        }
        U16x8 bl[16];
        int j0g = jlo + jb + g * 4;      if (j0g > Nn - 4) j0g = Nn - 4;
        int j1g = jlo + jb + 16 + g * 4; if (j1g > Nn - 4) j1g = Nn - 4;
#pragma unroll
        for (int nf = 0; nf < 16; ++nf) {
            int d = w * 256 + nf * 16 + lm;
            const bf16_t* vp = vbase + (size_t)d * Nn;
            bl[nf].u[0] = *(const uint2*)(vp + j0g);
            bl[nf].u[1] = *(const uint2*)(vp + j1g);
        }
#pragma unroll
        for (int nf = 0; nf < 16; ++nf)
#pragma unroll
            for (int f = 0; f < 2; ++f)
                oacc[f][nf] = __builtin_amdgcn_mfma_f32_16x16x32_bf16(pf[f], bl[nf].v, oacc[f][nf], 0, 0, 0);
    }

#pragma unroll
    for (int f = 0; f < 2; ++f) {
#pragma unroll
        for (int r = 0; r < 4; ++r) {
            int qq = f * 16 + g * 4 + r;
            float rs = rowrsum[qq];
            size_t rowg = (size_t)(b * Nn + q0 + qq) * Dd;
#pragma unroll
            for (int nf = 0; nf < 16; ++nf) {
                int d = w * 256 + nf * 16 + lm;
                AO[rowg + d] = (bf16_t)(oacc[f][nf][r] * rs);
            }
        }
    }
}

extern "C" void kernel_launch(void* const* d_in, const int* in_sizes, int n_in,
                              void* d_out, int out_size, void* d_ws, size_t ws_size,
                              hipStream_t stream)
{
    (void)in_sizes; (void)n_in; (void)out_size; (void)ws_size;
    const float* x      = (const float*)d_in[0];
    const float* w_qkv  = (const float*)d_in[1];
    const float* b_qkv  = (const float*)d_in[2];
    const float* w_proj = (const float*)d_in[3];
    const float* b_proj = (const float*)d_in[4];
    const int*   wsz    = (const int*)d_in[5];
    float* out = (float*)d_out;

    constexpr int Bb = 4, Nn = 2048, Dd = 1024;
    constexpr int M = Bb * Nn, N3 = 3 * Dd;

    char* p = (char*)d_ws;
    bf16_t* xb     = (bf16_t*)p; p += (size_t)M * Dd * 2;
    bf16_t* wqkvT  = (bf16_t*)p; p += (size_t)N3 * Dd * 2;
    bf16_t* wprojT = (bf16_t*)p; p += (size_t)Dd * Dd * 2;
    bf16_t* qb     = (bf16_t*)p; p += (size_t)M * Dd * 2;
    bf16_t* kb     = (bf16_t*)p; p += (size_t)M * Dd * 2;
    bf16_t* vtb    = (bf16_t*)p; p += (size_t)M * Dd * 2;
    bf16_t* ao     = xb;  // alias: xb dead after QKV GEMM

    k_convert_bf16<<<2048, 256, 0, stream>>>(x, xb, M * Dd / 4);
    k_transpose_bf16<<<dim3(N3 / 32, Dd / 32), 256, 0, stream>>>(w_qkv, wqkvT, Dd, N3);
    k_transpose_bf16<<<dim3(Dd / 32, Dd / 32), 256, 0, stream>>>(w_proj, wprojT, Dd, Dd);
    gemm_bt<0><<<1536, 256, 0, stream>>>(xb, wqkvT, b_qkv, qb, kb, vtb, 24, N3, Dd);
    k_attn<<<Bb * (Nn / 32), 256, 0, stream>>>(qb, kb, vtb, ao, wsz);
    gemm_bt<1><<<512, 256, 0, stream>>>(ao, wprojT, b_proj, out, nullptr, nullptr, 8, Dd, Dd);
}

// Round 10
// 291.650 us; speedup vs baseline: 1.7879x; 1.0171x over previous
//
#include <hip/hip_runtime.h>
#include <stdint.h>

typedef __bf16 bf16_t;
typedef __bf16 bf16x8 __attribute__((ext_vector_type(8)));
typedef __bf16 bf16x4 __attribute__((ext_vector_type(4)));
typedef float  f32x4  __attribute__((ext_vector_type(4)));

union U16x8 { uint2 u[2]; bf16x8 v; };

// async global->LDS, 16B per lane. LDS dest must be wave-uniform-base + lane*16.
__device__ __forceinline__ void gl_lds16(const void* g, void* l)
{
#if __has_builtin(__builtin_amdgcn_global_load_lds)
    __builtin_amdgcn_global_load_lds(
        (const __attribute__((address_space(1))) unsigned int*)g,
        (__attribute__((address_space(3))) unsigned int*)l, 16, 0, 0);
#else
    *(uint4*)l = *(const uint4*)g;
#endif
}

// ---------------- f32 -> bf16 convert (vectorized) ----------------
__global__ void k_convert_bf16(const float* __restrict__ in, bf16_t* __restrict__ out, int n4)
{
    int i = blockIdx.x * blockDim.x + threadIdx.x;
    const int stride = gridDim.x * blockDim.x;
    for (; i < n4; i += stride) {
        float4 v = ((const float4*)in)[i];
        bf16x4 o;
        o[0] = (bf16_t)v.x; o[1] = (bf16_t)v.y; o[2] = (bf16_t)v.z; o[3] = (bf16_t)v.w;
        ((bf16x4*)out)[i] = o;
    }
}

// ---------------- transpose f32 [R][C] -> bf16 [C][R] ----------------
__global__ void k_transpose_bf16(const float* __restrict__ in, bf16_t* __restrict__ out, int R, int C)
{
    __shared__ float tile[32][33];
    const int c0 = blockIdx.x * 32, r0 = blockIdx.y * 32;
    const int tid = threadIdx.x;
    const int c = tid & 31, r = tid >> 5;
#pragma unroll
    for (int i = 0; i < 4; ++i)
        tile[r + i * 8][c] = in[(size_t)(r0 + r + i * 8) * C + (c0 + c)];
    __syncthreads();
#pragma unroll
    for (int i = 0; i < 4; ++i)
        out[(size_t)(c0 + r + i * 8) * R + (r0 + c)] = (bf16_t)tile[c][r + i * 8];
}

// ---------------- GEMM: C[M][N] = A[M][K] * Bt[N][K]^T + bias ----------------
// MODE 0: qkv split-writer (q,k row-major bf16; v transposed to [B][D][N] bf16)
// MODE 1: f32 out + bias (proj) — direct stores are already full-64B-line coalesced
// Staging: global_load_lds w=16, LINEAR LDS dest, pre-swizzled global source
// (byte XOR (r&7)<<4 within the 128B row), swizzled ds_read on consume.
template<int MODE>
__global__ __launch_bounds__(256, 2)
void gemm_bt(const bf16_t* __restrict__ A, const bf16_t* __restrict__ Bt,
             const float* __restrict__ bias,
             void* __restrict__ out0, void* __restrict__ out1, void* __restrict__ out2,
             int nbx, int Nn, int K)
{
    __shared__ __align__(16) char smem[34816];   // As 16K + Bs 16K; epilogue: 128x136 bf16 tile
    bf16_t* As = (bf16_t*)smem;
    bf16_t* Bs = (bf16_t*)(smem + 16384);

    const int tid = threadIdx.x;
    const int lane = tid & 63;
    const int w = tid >> 6;
    const int wm = w >> 1, wn = w & 1;
    const int lm = lane & 15, g = lane >> 4;

    // bijective XCD swizzle (gridDim.x % 8 == 0 for both instantiations)
    const int nwg = gridDim.x;
    const int bid = (blockIdx.x & 7) * (nwg >> 3) + (blockIdx.x >> 3);
    const int bx = bid % nbx, by = bid / nbx;
    const int row0 = by * 128, col0 = bx * 128;

    f32x4 acc[4][4];
#pragma unroll
    for (int i = 0; i < 4; ++i)
#pragma unroll
        for (int j = 0; j < 4; ++j) {
            acc[i][j][0] = 0.f; acc[i][j][1] = 0.f; acc[i][j][2] = 0.f; acc[i][j][3] = 0.f;
        }

    const int nkb = K >> 6;
    for (int kb = 0; kb < nkb; ++kb) {
#pragma unroll
        for (int it = 0; it < 4; ++it) {
            int blk = it * 256 + tid;       // 16B chunk index of the 128x64 tile
            int r = blk >> 3;               // tile row
            int cb = (blk & 7) << 4;        // byte within row (linear LDS dest)
            int sb = cb ^ ((r & 7) << 4);   // pre-swizzled global source byte
            gl_lds16((const char*)(A  + (size_t)(row0 + r) * K + kb * 64) + sb, (char*)As + blk * 16);
            gl_lds16((const char*)(Bt + (size_t)(col0 + r) * K + kb * 64) + sb, (char*)Bs + blk * 16);
        }
        __syncthreads();   // drains vmcnt(0) -> tiles ready
#pragma unroll
        for (int kk = 0; kk < 2; ++kk) {
            bf16x8 af[4], bfr[4];
#pragma unroll
            for (int f = 0; f < 4; ++f) {
                int ra = wm * 64 + f * 16 + lm;
                int swa = (ra & 7) << 4;
                int c0b = kk * 64 + g * 8;
                U16x8 u;
                u.u[0] = *(const uint2*)((const char*)As + ra * 128 + (c0b ^ swa));
                u.u[1] = *(const uint2*)((const char*)As + ra * 128 + ((c0b + 32) ^ swa));
                af[f] = u.v;
                int rb = wn * 64 + f * 16 + lm;
                int swb = (rb & 7) << 4;
                U16x8 ub;
                ub.u[0] = *(const uint2*)((const char*)Bs + rb * 128 + (c0b ^ swb));
                ub.u[1] = *(const uint2*)((const char*)Bs + rb * 128 + ((c0b + 32) ^ swb));
                bfr[f] = ub.v;
            }
#pragma unroll
            for (int i = 0; i < 4; ++i)
#pragma unroll
                for (int j = 0; j < 4; ++j)
                    acc[i][j] = __builtin_amdgcn_mfma_f32_16x16x32_bf16(af[i], bfr[j], acc[i][j], 0, 0, 0);
        }
        __syncthreads();   // compute done before next tile overwrites LDS
    }

    // ---- epilogue: C col = lane&15, row = 4*(lane>>4)+reg [HW-verified] ----
    if constexpr (MODE == 1) {
        float* oo = (float*)out0;
#pragma unroll
        for (int j = 0; j < 4; ++j) {
            int ncol = col0 + wn * 64 + j * 16 + lm;
            float bv = bias[ncol];
#pragma unroll
            for (int i = 0; i < 4; ++i) {
                int rbase = row0 + wm * 64 + i * 16 + g * 4;
#pragma unroll
                for (int r = 0; r < 4; ++r)
                    oo[(size_t)(rbase + r) * Nn + ncol] = acc[i][j][r] + bv;
            }
        }
    } else {
        bf16_t* tile = (bf16_t*)smem;      // [128][136] bf16 (pad keeps 16B row align)
        constexpr int TP = 136;
        const int region = col0 >> 10;     // 0=q, 1=k, 2=v (block never straddles)
        if (region < 2) {
            // row-major restage -> coalesced 16B/lane stores
#pragma unroll
            for (int j = 0; j < 4; ++j) {
                int cl = wn * 64 + j * 16 + lm;
                float bv = bias[col0 + cl];
#pragma unroll
                for (int i = 0; i < 4; ++i) {
                    int rl = wm * 64 + i * 16 + g * 4;
#pragma unroll
                    for (int r = 0; r < 4; ++r)
                        tile[(rl + r) * TP + cl] = (bf16_t)(acc[i][j][r] + bv);
                }
            }
            __syncthreads();
            bf16_t* dst = (region == 0) ? (bf16_t*)out0 : (bf16_t*)out1;
            const int colbase = col0 & 1023;
            // full tile = 128 rows x 16 chunks of 8 bf16 = 2048 chunks -> 8 iters x 256 threads
#pragma unroll
            for (int it = 0; it < 8; ++it) {
                int blk = it * 256 + tid;
                int rr = blk >> 4;
                int c8 = (blk & 15) * 8;
                uint4 v = *(const uint4*)&tile[rr * TP + c8];
                *(uint4*)(dst + (size_t)(row0 + rr) * 1024 + colbase + c8) = v;
            }
        } else {
            // v: transposed restage (tileT[col][row]) -> coalesced [B][D][N] stores
#pragma unroll
            for (int j = 0; j < 4; ++j) {
                int cl = wn * 64 + j * 16 + lm;
                float bv = bias[col0 + cl];
#pragma unroll
                for (int i = 0; i < 4; ++i) {
                    int rl = wm * 64 + i * 16 + g * 4;
                    bf16x4 pk;
#pragma unroll
                    for (int r = 0; r < 4; ++r) pk[r] = (bf16_t)(acc[i][j][r] + bv);
                    *(bf16x4*)&tile[cl * TP + rl] = pk;     // 8B, aligned
                }
            }
            __syncthreads();
            bf16_t* vo = (bf16_t*)out2;
            const int bb = row0 >> 11;         // batch (2048 rows per batch; block never straddles)
            const int n0 = row0 & 2047;
            const int dbase = col0 - 2048;
#pragma unroll
            for (int it = 0; it < 8; ++it) {
                int blk = it * 256 + tid;
                int dl = blk >> 4;
                int n8 = (blk & 15) * 8;
                uint4 v = *(const uint4*)&tile[dl * TP + n8];
                *(uint4*)(vo + (size_t)bb * (1024 * 2048) + (size_t)(dbase + dl) * 2048 + (n0 + n8)) = v;
            }
        }
    }
}

// ---------------- local attention ----------------
// 32 queries per block, 4 waves. Fixed 288-key strip [jlo, jlo+288), window mask per element.
// Q[BN][D], K[BN][D] row-major bf16; V pre-transposed: Vt[B][D][N] bf16.
// XCD-aware remap: HW sends hw-block i to XCD i%8; give each XCD 32 CONSECUTIVE
// q-tiles so adjacent blocks (sharing 256/288 of their K/V strips) hit the same L2.
__global__ __launch_bounds__(256, 1)
void k_attn(const bf16_t* __restrict__ Q, const bf16_t* __restrict__ Km,
            const bf16_t* __restrict__ Vt, bf16_t* __restrict__ AO,
            const int* __restrict__ wptr)
{
    constexpr int Nn = 2048, Dd = 1024;
    constexpr int NJT = 18, JROWS = 288;
    __shared__ bf16_t Qs[32][1032];
    __shared__ bf16_t Ks[16][1032];
    __shared__ float  St[JROWS][33];
    __shared__ float  Spart[4][16][36];
    __shared__ float  red[8][32];
    __shared__ float  rowrsum[32];

    const int tid = threadIdx.x;
    const int lane = tid & 63;
    const int w = tid >> 6;
    const int lm = lane & 15, g = lane >> 4;
    // bijective on the 256-block grid: XCD x gets logical tiles [x*32, x*32+32)
    const int lblk = (blockIdx.x & 7) * 32 + (blockIdx.x >> 3);
    const int b = lblk >> 6;
    const int q0 = (lblk & 63) * 32;
    const int win = *wptr;
    int jlo = q0 - win; if (jlo < 0) jlo = 0;

    {
        const bf16_t* src = Q + ((size_t)(b * Nn + q0)) * Dd;
#pragma unroll
        for (int i = 0; i < 16; ++i) {
            int b16 = i * 256 + tid;
            int r = b16 >> 7;
            int ce = (b16 & 127) * 8;
            uint4 v = *(const uint4*)(src + (size_t)r * Dd + ce);
            *(uint4*)(&Qs[r][ce]) = v;
        }
    }

    for (int jt = 0; jt < NJT; ++jt) {
        __syncthreads();
#pragma unroll
        for (int i = 0; i < 8; ++i) {
            int b16 = i * 256 + tid;
            int r = b16 >> 7;
            int ce = (b16 & 127) * 8;
            int jg = jlo + jt * 16 + r;
            uint4 v = make_uint4(0u, 0u, 0u, 0u);
            if (jg < Nn) v = *(const uint4*)(Km + ((size_t)(b * Nn + jg)) * Dd + ce);
            *(uint4*)(&Ks[r][ce]) = v;
        }
        __syncthreads();
        f32x4 sacc[2];
#pragma unroll
        for (int f = 0; f < 2; ++f) { sacc[f][0]=0.f; sacc[f][1]=0.f; sacc[f][2]=0.f; sacc[f][3]=0.f; }
#pragma unroll
        for (int ks = 0; ks < 8; ++ks) {
            int d0 = w * 256 + ks * 32;
            U16x8 kf;
            kf.u[0] = *(const uint2*)(&Ks[lm][d0 + g * 4]);
            kf.u[1] = *(const uint2*)(&Ks[lm][d0 + 16 + g * 4]);
#pragma unroll
            for (int f = 0; f < 2; ++f) {
                U16x8 qf;
                qf.u[0] = *(const uint2*)(&Qs[f * 16 + lm][d0 + g * 4]);
                qf.u[1] = *(const uint2*)(&Qs[f * 16 + lm][d0 + 16 + g * 4]);
                sacc[f] = __builtin_amdgcn_mfma_f32_16x16x32_bf16(qf.v, kf.v, sacc[f], 0, 0, 0);
            }
        }
#pragma unroll
        for (int f = 0; f < 2; ++f)
            *(f32x4*)(&Spart[w][lm][f * 16 + g * 4]) = sacc[f];
        __syncthreads();
        {
            int j = tid >> 4;
            int q2 = (tid & 15) * 2;
#pragma unroll
            for (int t = 0; t < 2; ++t) {
                int qq = q2 + t;
                float s = Spart[0][j][qq] + Spart[1][j][qq] + Spart[2][j][qq] + Spart[3][j][qq];
                s *= 0.03125f;
                int jg = jlo + jt * 16 + j;
                int qg = q0 + qq;
                int dd = qg - jg; if (dd < 0) dd = -dd;
                bool valid = (jg < Nn) && (dd <= win);
                St[jt * 16 + j][qq] = valid ? s : -3.0e38f;
            }
        }
    }
    __syncthreads();

    {
        int qq = tid & 31, sub = tid >> 5;
        float m = -3.0e38f;
        for (int j = sub; j < JROWS; j += 8) m = fmaxf(m, St[j][qq]);
        red[sub][qq] = m;
        __syncthreads();
        float mm = red[0][qq];
#pragma unroll
        for (int s2 = 1; s2 < 8; ++s2) mm = fmaxf(mm, red[s2][qq]);
        __syncthreads();
        float sum = 0.f;
        for (int j = sub; j < JROWS; j += 8) {
            float p = __expf(St[j][qq] - mm);
            St[j][qq] = p;
            sum += p;
        }
        red[sub][qq] = sum;
        __syncthreads();
        float ss = 0.f;
#pragma unroll
        for (int s2 = 0; s2 < 8; ++s2) ss += red[s2][qq];
        if (sub == 0) rowrsum[qq] = 1.f / ss;
    }
    __syncthreads();

    f32x4 oacc[2][16];
#pragma unroll
    for (int f = 0; f < 2; ++f)
#pragma unroll
        for (int nf = 0; nf < 16; ++nf) { oacc[f][nf][0]=0.f; oacc[f][nf][1]=0.f; oacc[f][nf][2]=0.f; oacc[f][nf][3]=0.f; }

    const bf16_t* vbase = Vt + (size_t)b * Dd * Nn;
#pragma unroll 1
    for (int ks = 0; ks < 9; ++ks) {
        int jb = ks * 32;
        bf16x8 pf[2];
#pragma unroll
        for (int f = 0; f < 2; ++f) {
            int qq = f * 16 + lm;
            bf16x8 v;
#pragma unroll
            for (int h = 0; h < 2; ++h)
#pragma unroll
                for (int i2 = 0; i2 < 4; ++i2)
                    v[h * 4 + i2] = (bf16_t)St[jb + h * 16 + g * 4 + i2][qq];
            pf[f] = v;
        }
        U16x8 bl[16];
        int j0g = jlo + jb + g * 4;      if (j0g > Nn - 4) j0g = Nn - 4;
        int j1g = jlo + jb + 16 + g * 4; if (j1g > Nn - 4) j1g = Nn - 4;
#pragma unroll
        for (int nf = 0; nf < 16; ++nf) {
            int d = w * 256 + nf * 16 + lm;
            const bf16_t* vp = vbase + (size_t)d * Nn;
            bl[nf].u[0] = *(const uint2*)(vp + j0g);
            bl[nf].u[1] = *(const uint2*)(vp + j1g);
        }
#pragma unroll
        for (int nf = 0; nf < 16; ++nf)
#pragma unroll
            for (int f = 0; f < 2; ++f)
                oacc[f][nf] = __builtin_amdgcn_mfma_f32_16x16x32_bf16(pf[f], bl[nf].v, oacc[f][nf], 0, 0, 0);
    }

#pragma unroll
    for (int f = 0; f < 2; ++f) {
#pragma unroll
        for (int r = 0; r < 4; ++r) {
            int qq = f * 16 + g * 4 + r;
            float rs = rowrsum[qq];
            size_t rowg = (size_t)(b * Nn + q0 + qq) * Dd;
#pragma unroll
            for (int nf = 0; nf < 16; ++nf) {
                int d = w * 256 + nf * 16 + lm;
                AO[rowg + d] = (bf16_t)(oacc[f][nf][r] * rs);
            }
        }
    }
}

extern "C" void kernel_launch(void* const* d_in, const int* in_sizes, int n_in,
                              void* d_out, int out_size, void* d_ws, size_t ws_size,
                              hipStream_t stream)
{
    (void)in_sizes; (void)n_in; (void)out_size; (void)ws_size;
    const float* x      = (const float*)d_in[0];
    const float* w_qkv  = (const float*)d_in[1];
    const float* b_qkv  = (const float*)d_in[2];
    const float* w_proj = (const float*)d_in[3];
    const float* b_proj = (const float*)d_in[4];
    const int*   wsz    = (const int*)d_in[5];
    float* out = (float*)d_out;

    constexpr int Bb = 4, Nn = 2048, Dd = 1024;
    constexpr int M = Bb * Nn, N3 = 3 * Dd;

    char* p = (char*)d_ws;
    bf16_t* xb     = (bf16_t*)p; p += (size_t)M * Dd * 2;
    bf16_t* wqkvT  = (bf16_t*)p; p += (size_t)N3 * Dd * 2;
    bf16_t* wprojT = (bf16_t*)p; p += (size_t)Dd * Dd * 2;
    bf16_t* qb     = (bf16_t*)p; p += (size_t)M * Dd * 2;
    bf16_t* kb     = (bf16_t*)p; p += (size_t)M * Dd * 2;
    bf16_t* vtb    = (bf16_t*)p; p += (size_t)M * Dd * 2;
    bf16_t* ao     = xb;  // alias: xb dead after QKV GEMM

    k_convert_bf16<<<2048, 256, 0, stream>>>(x, xb, M * Dd / 4);
    k_transpose_bf16<<<dim3(N3 / 32, Dd / 32), 256, 0, stream>>>(w_qkv, wqkvT, Dd, N3);
    k_transpose_bf16<<<dim3(Dd / 32, Dd / 32), 256, 0, stream>>>(w_proj, wprojT, Dd, Dd);
    gemm_bt<0><<<1536, 256, 0, stream>>>(xb, wqkvT, b_qkv, qb, kb, vtb, 24, N3, Dd);
    k_attn<<<Bb * (Nn / 32), 256, 0, stream>>>(qb, kb, vtb, ao, wsz);
    gemm_bt<1><<<512, 256, 0, stream>>>(ao, wprojT, b_proj, out, nullptr, nullptr, 8, Dd, Dd);
}

// Round 12
// 272.252 us; speedup vs baseline: 1.9153x; 1.0713x over previous
//
#include <hip/hip_runtime.h>
#include <stdint.h>

typedef __bf16 bf16_t;
typedef __bf16 bf16x8 __attribute__((ext_vector_type(8)));
typedef __bf16 bf16x4 __attribute__((ext_vector_type(4)));
typedef float  f32x4  __attribute__((ext_vector_type(4)));

union U16x8 { uint2 u[2]; bf16x8 v; };

// async global->LDS, 16B per lane. LDS dest must be wave-uniform-base + lane*16.
__device__ __forceinline__ void gl_lds16(const void* g, void* l)
{
#if __has_builtin(__builtin_amdgcn_global_load_lds)
    __builtin_amdgcn_global_load_lds(
        (const __attribute__((address_space(1))) unsigned int*)g,
        (__attribute__((address_space(3))) unsigned int*)l, 16, 0, 0);
#else
    *(uint4*)l = *(const uint4*)g;
#endif
}

// ---------------- f32 -> bf16 convert (vectorized) ----------------
__global__ void k_convert_bf16(const float* __restrict__ in, bf16_t* __restrict__ out, int n4)
{
    int i = blockIdx.x * blockDim.x + threadIdx.x;
    const int stride = gridDim.x * blockDim.x;
    for (; i < n4; i += stride) {
        float4 v = ((const float4*)in)[i];
        bf16x4 o;
        o[0] = (bf16_t)v.x; o[1] = (bf16_t)v.y; o[2] = (bf16_t)v.z; o[3] = (bf16_t)v.w;
        ((bf16x4*)out)[i] = o;
    }
}

// ---------------- transpose f32 [R][C] -> bf16 [C][R] ----------------
__global__ void k_transpose_bf16(const float* __restrict__ in, bf16_t* __restrict__ out, int R, int C)
{
    __shared__ float tile[32][33];
    const int c0 = blockIdx.x * 32, r0 = blockIdx.y * 32;
    const int tid = threadIdx.x;
    const int c = tid & 31, r = tid >> 5;
#pragma unroll
    for (int i = 0; i < 4; ++i)
        tile[r + i * 8][c] = in[(size_t)(r0 + r + i * 8) * C + (c0 + c)];
    __syncthreads();
#pragma unroll
    for (int i = 0; i < 4; ++i)
        out[(size_t)(c0 + r + i * 8) * R + (r0 + c)] = (bf16_t)tile[c][r + i * 8];
}

// ---------------- GEMM: C[M][N] = A[M][K] * Bt[N][K]^T + bias ----------------
// MODE 0: qkv split-writer (q,k row-major bf16; v transposed to [B][D][N] bf16)
// MODE 1: f32 out + bias (proj) — direct stores are already full-64B-line coalesced
template<int MODE>
__global__ __launch_bounds__(256, 2)
void gemm_bt(const bf16_t* __restrict__ A, const bf16_t* __restrict__ Bt,
             const float* __restrict__ bias,
             void* __restrict__ out0, void* __restrict__ out1, void* __restrict__ out2,
             int nbx, int Nn, int K)
{
    __shared__ __align__(16) char smem[34816];   // As 16K + Bs 16K; epilogue: 128x136 bf16 tile
    bf16_t* As = (bf16_t*)smem;
    bf16_t* Bs = (bf16_t*)(smem + 16384);

    const int tid = threadIdx.x;
    const int lane = tid & 63;
    const int w = tid >> 6;
    const int wm = w >> 1, wn = w & 1;
    const int lm = lane & 15, g = lane >> 4;

    // bijective XCD swizzle (gridDim.x % 8 == 0 for both instantiations)
    const int nwg = gridDim.x;
    const int bid = (blockIdx.x & 7) * (nwg >> 3) + (blockIdx.x >> 3);
    const int bx = bid % nbx, by = bid / nbx;
    const int row0 = by * 128, col0 = bx * 128;

    f32x4 acc[4][4];
#pragma unroll
    for (int i = 0; i < 4; ++i)
#pragma unroll
        for (int j = 0; j < 4; ++j) {
            acc[i][j][0] = 0.f; acc[i][j][1] = 0.f; acc[i][j][2] = 0.f; acc[i][j][3] = 0.f;
        }

    const int nkb = K >> 6;
    for (int kb = 0; kb < nkb; ++kb) {
#pragma unroll
        for (int it = 0; it < 4; ++it) {
            int blk = it * 256 + tid;       // 16B chunk index of the 128x64 tile
            int r = blk >> 3;               // tile row
            int cb = (blk & 7) << 4;        // byte within row (linear LDS dest)
            int sb = cb ^ ((r & 7) << 4);   // pre-swizzled global source byte
            gl_lds16((const char*)(A  + (size_t)(row0 + r) * K + kb * 64) + sb, (char*)As + blk * 16);
            gl_lds16((const char*)(Bt + (size_t)(col0 + r) * K + kb * 64) + sb, (char*)Bs + blk * 16);
        }
        __syncthreads();   // drains vmcnt(0) -> tiles ready
#pragma unroll
        for (int kk = 0; kk < 2; ++kk) {
            bf16x8 af[4], bfr[4];
#pragma unroll
            for (int f = 0; f < 4; ++f) {
                int ra = wm * 64 + f * 16 + lm;
                int swa = (ra & 7) << 4;
                int c0b = kk * 64 + g * 8;
                U16x8 u;
                u.u[0] = *(const uint2*)((const char*)As + ra * 128 + (c0b ^ swa));
                u.u[1] = *(const uint2*)((const char*)As + ra * 128 + ((c0b + 32) ^ swa));
                af[f] = u.v;
                int rb = wn * 64 + f * 16 + lm;
                int swb = (rb & 7) << 4;
                U16x8 ub;
                ub.u[0] = *(const uint2*)((const char*)Bs + rb * 128 + (c0b ^ swb));
                ub.u[1] = *(const uint2*)((const char*)Bs + rb * 128 + ((c0b + 32) ^ swb));
                bfr[f] = ub.v;
            }
#pragma unroll
            for (int i = 0; i < 4; ++i)
#pragma unroll
                for (int j = 0; j < 4; ++j)
                    acc[i][j] = __builtin_amdgcn_mfma_f32_16x16x32_bf16(af[i], bfr[j], acc[i][j], 0, 0, 0);
        }
        __syncthreads();   // compute done before next tile overwrites LDS
    }

    // ---- epilogue: C col = lane&15, row = 4*(lane>>4)+reg [HW-verified] ----
    if constexpr (MODE == 1) {
        float* oo = (float*)out0;
#pragma unroll
        for (int j = 0; j < 4; ++j) {
            int ncol = col0 + wn * 64 + j * 16 + lm;
            float bv = bias[ncol];
#pragma unroll
            for (int i = 0; i < 4; ++i) {
                int rbase = row0 + wm * 64 + i * 16 + g * 4;
#pragma unroll
                for (int r = 0; r < 4; ++r)
                    oo[(size_t)(rbase + r) * Nn + ncol] = acc[i][j][r] + bv;
            }
        }
    } else {
        bf16_t* tile = (bf16_t*)smem;      // [128][136] bf16 (pad keeps 16B row align)
        constexpr int TP = 136;
        const int region = col0 >> 10;     // 0=q, 1=k, 2=v (block never straddles)
        if (region < 2) {
            // row-major restage -> coalesced 16B/lane stores
#pragma unroll
            for (int j = 0; j < 4; ++j) {
                int cl = wn * 64 + j * 16 + lm;
                float bv = bias[col0 + cl];
#pragma unroll
                for (int i = 0; i < 4; ++i) {
                    int rl = wm * 64 + i * 16 + g * 4;
#pragma unroll
                    for (int r = 0; r < 4; ++r)
                        tile[(rl + r) * TP + cl] = (bf16_t)(acc[i][j][r] + bv);
                }
            }
            __syncthreads();
            bf16_t* dst = (region == 0) ? (bf16_t*)out0 : (bf16_t*)out1;
            const int colbase = col0 & 1023;
            // full tile = 128 rows x 16 chunks of 8 bf16 = 2048 chunks -> 8 iters x 256 threads
#pragma unroll
            for (int it = 0; it < 8; ++it) {
                int blk = it * 256 + tid;
                int rr = blk >> 4;
                int c8 = (blk & 15) * 8;
                uint4 v = *(const uint4*)&tile[rr * TP + c8];
                *(uint4*)(dst + (size_t)(row0 + rr) * 1024 + colbase + c8) = v;
            }
        } else {
            // v: transposed restage (tileT[col][row]) -> coalesced [B][D][N] stores
#pragma unroll
            for (int j = 0; j < 4; ++j) {
                int cl = wn * 64 + j * 16 + lm;
                float bv = bias[col0 + cl];
#pragma unroll
                for (int i = 0; i < 4; ++i) {
                    int rl = wm * 64 + i * 16 + g * 4;
                    bf16x4 pk;
#pragma unroll
                    for (int r = 0; r < 4; ++r) pk[r] = (bf16_t)(acc[i][j][r] + bv);
                    *(bf16x4*)&tile[cl * TP + rl] = pk;     // 8B, aligned
                }
            }
            __syncthreads();
            bf16_t* vo = (bf16_t*)out2;
            const int bb = row0 >> 11;         // batch (2048 rows per batch; block never straddles)
            const int n0 = row0 & 2047;
            const int dbase = col0 - 2048;
#pragma unroll
            for (int it = 0; it < 8; ++it) {
                int blk = it * 256 + tid;
                int dl = blk >> 4;
                int n8 = (blk & 15) * 8;
                uint4 v = *(const uint4*)&tile[dl * TP + n8];
                *(uint4*)(vo + (size_t)bb * (1024 * 2048) + (size_t)(dbase + dl) * 2048 + (n0 + n8)) = v;
            }
        }
    }
}

// ---------------- local attention ----------------
// 32 queries per block, 8 waves (512 thr) so each SIMD holds 2 waves (latency hiding).
// Wave w owns d-chunk [w*128, w*128+128) for both QK^T partial-reduce and PV.
// Q[BN][D], K[BN][D] row-major bf16; V pre-transposed: Vt[B][D][N] bf16.
// XCD-aware remap keeps adjacent q-tiles on the same XCD L2 (FETCH 187->27MB, r10).
__global__ __launch_bounds__(512, 1)
void k_attn(const bf16_t* __restrict__ Q, const bf16_t* __restrict__ Km,
            const bf16_t* __restrict__ Vt, bf16_t* __restrict__ AO,
            const int* __restrict__ wptr)
{
    constexpr int Nn = 2048, Dd = 1024;
    constexpr int NJT = 18, JROWS = 288;
    __shared__ bf16_t Qs[32][1032];       // 66048 B
    __shared__ bf16_t Ks[16][1032];       // 33024 B
    __shared__ float  St[JROWS][33];      // 38016 B
    __shared__ float  Spart[8][16][36];   // 18432 B
    __shared__ float  red[16][32];        //  2048 B
    __shared__ float  rowrsum[32];        //   128 B   -> 157,696 B total

    const int tid = threadIdx.x;
    const int lane = tid & 63;
    const int w = tid >> 6;               // 0..7
    const int lm = lane & 15, g = lane >> 4;
    // bijective on the 256-block grid: XCD x gets logical tiles [x*32, x*32+32)
    const int lblk = (blockIdx.x & 7) * 32 + (blockIdx.x >> 3);
    const int b = lblk >> 6;
    const int q0 = (lblk & 63) * 32;
    const int win = *wptr;
    int jlo = q0 - win; if (jlo < 0) jlo = 0;

    // stage Q tile (32 x 1024): 4096 8-elem chunks / 512 threads = 8 iters
    {
        const bf16_t* src = Q + ((size_t)(b * Nn + q0)) * Dd;
#pragma unroll
        for (int i = 0; i < 8; ++i) {
            int c = i * 512 + tid;
            int r = c >> 7;
            int ce = (c & 127) * 8;
            *(uint4*)(&Qs[r][ce]) = *(const uint4*)(src + (size_t)r * Dd + ce);
        }
    }

    for (int jt = 0; jt < NJT; ++jt) {
        __syncthreads();
        // stage K tile (16 x 1024): 2048 chunks / 512 threads = 4 iters
#pragma unroll
        for (int i = 0; i < 4; ++i) {
            int c = i * 512 + tid;
            int r = c >> 7;
            int ce = (c & 127) * 8;
            int jg = jlo + jt * 16 + r;
            uint4 v = make_uint4(0u, 0u, 0u, 0u);
            if (jg < Nn) v = *(const uint4*)(Km + ((size_t)(b * Nn + jg)) * Dd + ce);
            *(uint4*)(&Ks[r][ce]) = v;
        }
        __syncthreads();
        f32x4 sacc[2];
#pragma unroll
        for (int f = 0; f < 2; ++f) { sacc[f][0]=0.f; sacc[f][1]=0.f; sacc[f][2]=0.f; sacc[f][3]=0.f; }
#pragma unroll
        for (int ks = 0; ks < 4; ++ks) {
            int d0 = w * 128 + ks * 32;
            U16x8 kf;
            kf.u[0] = *(const uint2*)(&Ks[lm][d0 + g * 4]);
            kf.u[1] = *(const uint2*)(&Ks[lm][d0 + 16 + g * 4]);
#pragma unroll
            for (int f = 0; f < 2; ++f) {
                U16x8 qf;
                qf.u[0] = *(const uint2*)(&Qs[f * 16 + lm][d0 + g * 4]);
                qf.u[1] = *(const uint2*)(&Qs[f * 16 + lm][d0 + 16 + g * 4]);
                sacc[f] = __builtin_amdgcn_mfma_f32_16x16x32_bf16(qf.v, kf.v, sacc[f], 0, 0, 0);
            }
        }
        // C layout: col=lane&15 -> j=lm ; row=4*(lane>>4)+r -> q=f*16+4g+r
#pragma unroll
        for (int f = 0; f < 2; ++f)
            *(f32x4*)(&Spart[w][lm][f * 16 + g * 4]) = sacc[f];
        __syncthreads();
        {
            int j = tid >> 5;          // 0..15
            int qq = tid & 31;         // 0..31  (16x32 = 512 exactly)
            float s = 0.f;
#pragma unroll
            for (int s2 = 0; s2 < 8; ++s2) s += Spart[s2][j][qq];
            s *= 0.03125f;  // D^-0.5
            int jg = jlo + jt * 16 + j;
            int qg = q0 + qq;
            int dd = qg - jg; if (dd < 0) dd = -dd;
            bool valid = (jg < Nn) && (dd <= win);
            St[jt * 16 + j][qq] = valid ? s : -3.0e38f;
        }
    }
    __syncthreads();

    // softmax over j per q column; 16 threads per q
    {
        int qq = tid & 31, sub = tid >> 5;   // sub 0..15
        float m = -3.0e38f;
        for (int j = sub; j < JROWS; j += 16) m = fmaxf(m, St[j][qq]);
        red[sub][qq] = m;
        __syncthreads();
        float mm = red[0][qq];
#pragma unroll
        for (int s2 = 1; s2 < 16; ++s2) mm = fmaxf(mm, red[s2][qq]);
        __syncthreads();   // all reads of red done before re-use
        float sum = 0.f;
        for (int j = sub; j < JROWS; j += 16) {
            float p = __expf(St[j][qq] - mm);
            St[j][qq] = p;
            sum += p;
        }
        red[sub][qq] = sum;
        __syncthreads();
        float ss = 0.f;
#pragma unroll
        for (int s2 = 0; s2 < 16; ++s2) ss += red[s2][qq];
        if (sub == 0) rowrsum[qq] = 1.f / ss;
    }
    __syncthreads();

    // PV: wave w owns output d-chunk [w*128, w*128+128)
    f32x4 oacc[2][8];
#pragma unroll
    for (int f = 0; f < 2; ++f)
#pragma unroll
        for (int nf = 0; nf < 8; ++nf) { oacc[f][nf][0]=0.f; oacc[f][nf][1]=0.f; oacc[f][nf][2]=0.f; oacc[f][nf][3]=0.f; }

    const bf16_t* vbase = Vt + (size_t)b * Dd * Nn;
#pragma unroll 1
    for (int ks = 0; ks < 9; ++ks) {   // 288/32
        int jb = ks * 32;
        bf16x8 pf[2];
#pragma unroll
        for (int f = 0; f < 2; ++f) {
            int qq = f * 16 + lm;
            bf16x8 v;
#pragma unroll
            for (int h = 0; h < 2; ++h)
#pragma unroll
                for (int i2 = 0; i2 < 4; ++i2)
                    v[h * 4 + i2] = (bf16_t)St[jb + h * 16 + g * 4 + i2][qq];
            pf[f] = v;
        }
        U16x8 bl[8];
        int j0g = jlo + jb + g * 4;      if (j0g > Nn - 4) j0g = Nn - 4;   // clamped lanes have p=0
        int j1g = jlo + jb + 16 + g * 4; if (j1g > Nn - 4) j1g = Nn - 4;
#pragma unroll
        for (int nf = 0; nf < 8; ++nf) {
            int d = w * 128 + nf * 16 + lm;
            const bf16_t* vp = vbase + (size_t)d * Nn;
            bl[nf].u[0] = *(const uint2*)(vp + j0g);
            bl[nf].u[1] = *(const uint2*)(vp + j1g);
        }
#pragma unroll
        for (int nf = 0; nf < 8; ++nf)
#pragma unroll
            for (int f = 0; f < 2; ++f)
                oacc[f][nf] = __builtin_amdgcn_mfma_f32_16x16x32_bf16(pf[f], bl[nf].v, oacc[f][nf], 0, 0, 0);
    }

    // epilogue: scale by 1/sum, write bf16
#pragma unroll
    for (int f = 0; f < 2; ++f) {
#pragma unroll
        for (int r = 0; r < 4; ++r) {
            int qq = f * 16 + g * 4 + r;
            float rs = rowrsum[qq];
            size_t rowg = (size_t)(b * Nn + q0 + qq) * Dd;
#pragma unroll
            for (int nf = 0; nf < 8; ++nf) {
                int d = w * 128 + nf * 16 + lm;
                AO[rowg + d] = (bf16_t)(oacc[f][nf][r] * rs);
            }
        }
    }
}

extern "C" void kernel_launch(void* const* d_in, const int* in_sizes, int n_in,
                              void* d_out, int out_size, void* d_ws, size_t ws_size,
                              hipStream_t stream)
{
    (void)in_sizes; (void)n_in; (void)out_size; (void)ws_size;
    const float* x      = (const float*)d_in[0];
    const float* w_qkv  = (const float*)d_in[1];
    const float* b_qkv  = (const float*)d_in[2];
    const float* w_proj = (const float*)d_in[3];
    const float* b_proj = (const float*)d_in[4];
    const int*   wsz    = (const int*)d_in[5];
    float* out = (float*)d_out;

    constexpr int Bb = 4, Nn = 2048, Dd = 1024;
    constexpr int M = Bb * Nn, N3 = 3 * Dd;

    char* p = (char*)d_ws;
    bf16_t* xb     = (bf16_t*)p; p += (size_t)M * Dd * 2;
    bf16_t* wqkvT  = (bf16_t*)p; p += (size_t)N3 * Dd * 2;
    bf16_t* wprojT = (bf16_t*)p; p += (size_t)Dd * Dd * 2;
    bf16_t* qb     = (bf16_t*)p; p += (size_t)M * Dd * 2;
    bf16_t* kb     = (bf16_t*)p; p += (size_t)M * Dd * 2;
    bf16_t* vtb    = (bf16_t*)p; p += (size_t)M * Dd * 2;
    bf16_t* ao     = xb;  // alias: xb dead after QKV GEMM

    k_convert_bf16<<<2048, 256, 0, stream>>>(x, xb, M * Dd / 4);
    k_transpose_bf16<<<dim3(N3 / 32, Dd / 32), 256, 0, stream>>>(w_qkv, wqkvT, Dd, N3);
    k_transpose_bf16<<<dim3(Dd / 32, Dd / 32), 256, 0, stream>>>(w_proj, wprojT, Dd, Dd);
    gemm_bt<0><<<1536, 256, 0, stream>>>(xb, wqkvT, b_qkv, qb, kb, vtb, 24, N3, Dd);
    k_attn<<<Bb * (Nn / 32), 512, 0, stream>>>(qb, kb, vtb, ao, wsz);
    gemm_bt<1><<<512, 256, 0, stream>>>(ao, wprojT, b_proj, out, nullptr, nullptr, 8, Dd, Dd);
}

// Round 13
// 253.352 us; speedup vs baseline: 2.0582x; 1.0746x over previous
//
#include <hip/hip_runtime.h>
#include <stdint.h>

typedef __bf16 bf16_t;
typedef __bf16 bf16x8 __attribute__((ext_vector_type(8)));
typedef __bf16 bf16x4 __attribute__((ext_vector_type(4)));
typedef float  f32x4  __attribute__((ext_vector_type(4)));

union U16x8 { uint2 u[2]; uint4 q; bf16x8 v; };

// async global->LDS, 16B per lane. LDS dest must be wave-uniform-base + lane*16.
__device__ __forceinline__ void gl_lds16(const void* g, void* l)
{
#if __has_builtin(__builtin_amdgcn_global_load_lds)
    __builtin_amdgcn_global_load_lds(
        (const __attribute__((address_space(1))) unsigned int*)g,
        (__attribute__((address_space(3))) unsigned int*)l, 16, 0, 0);
#else
    *(uint4*)l = *(const uint4*)g;
#endif
}

// ---------------- f32 -> bf16 convert (vectorized) ----------------
__global__ void k_convert_bf16(const float* __restrict__ in, bf16_t* __restrict__ out, int n4)
{
    int i = blockIdx.x * blockDim.x + threadIdx.x;
    const int stride = gridDim.x * blockDim.x;
    for (; i < n4; i += stride) {
        float4 v = ((const float4*)in)[i];
        bf16x4 o;
        o[0] = (bf16_t)v.x; o[1] = (bf16_t)v.y; o[2] = (bf16_t)v.z; o[3] = (bf16_t)v.w;
        ((bf16x4*)out)[i] = o;
    }
}

// ---------------- transpose f32 [R][C] -> bf16 [C][R] ----------------
__global__ void k_transpose_bf16(const float* __restrict__ in, bf16_t* __restrict__ out, int R, int C)
{
    __shared__ float tile[32][33];
    const int c0 = blockIdx.x * 32, r0 = blockIdx.y * 32;
    const int tid = threadIdx.x;
    const int c = tid & 31, r = tid >> 5;
#pragma unroll
    for (int i = 0; i < 4; ++i)
        tile[r + i * 8][c] = in[(size_t)(r0 + r + i * 8) * C + (c0 + c)];
    __syncthreads();
#pragma unroll
    for (int i = 0; i < 4; ++i)
        out[(size_t)(c0 + r + i * 8) * R + (r0 + c)] = (bf16_t)tile[c][r + i * 8];
}

// ---------------- GEMM: C[M][N] = A[M][K] * Bt[N][K]^T + bias ----------------
// MODE 0: qkv split-writer (q,k row-major bf16; v transposed to [B][D][N] bf16)
// MODE 1: f32 out + bias (proj)
template<int MODE>
__global__ __launch_bounds__(256, 2)
void gemm_bt(const bf16_t* __restrict__ A, const bf16_t* __restrict__ Bt,
             const float* __restrict__ bias,
             void* __restrict__ out0, void* __restrict__ out1, void* __restrict__ out2,
             int nbx, int Nn, int K)
{
    __shared__ __align__(16) char smem[34816];   // As 16K + Bs 16K; epilogue: 128x136 bf16 tile
    bf16_t* As = (bf16_t*)smem;
    bf16_t* Bs = (bf16_t*)(smem + 16384);

    const int tid = threadIdx.x;
    const int lane = tid & 63;
    const int w = tid >> 6;
    const int wm = w >> 1, wn = w & 1;
    const int lm = lane & 15, g = lane >> 4;

    // bijective XCD swizzle (gridDim.x % 8 == 0 for both instantiations)
    const int nwg = gridDim.x;
    const int bid = (blockIdx.x & 7) * (nwg >> 3) + (blockIdx.x >> 3);
    const int bx = bid % nbx, by = bid / nbx;
    const int row0 = by * 128, col0 = bx * 128;

    f32x4 acc[4][4];
#pragma unroll
    for (int i = 0; i < 4; ++i)
#pragma unroll
        for (int j = 0; j < 4; ++j) {
            acc[i][j][0] = 0.f; acc[i][j][1] = 0.f; acc[i][j][2] = 0.f; acc[i][j][3] = 0.f;
        }

    const int nkb = K >> 6;
    for (int kb = 0; kb < nkb; ++kb) {
#pragma unroll
        for (int it = 0; it < 4; ++it) {
            int blk = it * 256 + tid;       // 16B chunk index of the 128x64 tile
            int r = blk >> 3;               // tile row
            int cb = (blk & 7) << 4;        // byte within row (linear LDS dest)
            int sb = cb ^ ((r & 7) << 4);   // pre-swizzled global source byte
            gl_lds16((const char*)(A  + (size_t)(row0 + r) * K + kb * 64) + sb, (char*)As + blk * 16);
            gl_lds16((const char*)(Bt + (size_t)(col0 + r) * K + kb * 64) + sb, (char*)Bs + blk * 16);
        }
        __syncthreads();   // drains vmcnt(0) -> tiles ready
#pragma unroll
        for (int kk = 0; kk < 2; ++kk) {
            bf16x8 af[4], bfr[4];
#pragma unroll
            for (int f = 0; f < 4; ++f) {
                int ra = wm * 64 + f * 16 + lm;
                int swa = (ra & 7) << 4;
                int c0b = kk * 64 + g * 8;
                U16x8 u;
                u.u[0] = *(const uint2*)((const char*)As + ra * 128 + (c0b ^ swa));
                u.u[1] = *(const uint2*)((const char*)As + ra * 128 + ((c0b + 32) ^ swa));
                af[f] = u.v;
                int rb = wn * 64 + f * 16 + lm;
                int swb = (rb & 7) << 4;
                U16x8 ub;
                ub.u[0] = *(const uint2*)((const char*)Bs + rb * 128 + (c0b ^ swb));
                ub.u[1] = *(const uint2*)((const char*)Bs + rb * 128 + ((c0b + 32) ^ swb));
                bfr[f] = ub.v;
            }
#pragma unroll
            for (int i = 0; i < 4; ++i)
#pragma unroll
                for (int j = 0; j < 4; ++j)
                    acc[i][j] = __builtin_amdgcn_mfma_f32_16x16x32_bf16(af[i], bfr[j], acc[i][j], 0, 0, 0);
        }
        __syncthreads();   // compute done before next tile overwrites LDS
    }

    // ---- epilogue: C col = lane&15, row = 4*(lane>>4)+reg [HW-verified] ----
    if constexpr (MODE == 1) {
        float* oo = (float*)out0;
#pragma unroll
        for (int j = 0; j < 4; ++j) {
            int ncol = col0 + wn * 64 + j * 16 + lm;
            float bv = bias[ncol];
#pragma unroll
            for (int i = 0; i < 4; ++i) {
                int rbase = row0 + wm * 64 + i * 16 + g * 4;
#pragma unroll
                for (int r = 0; r < 4; ++r)
                    oo[(size_t)(rbase + r) * Nn + ncol] = acc[i][j][r] + bv;
            }
        }
    } else {
        bf16_t* tile = (bf16_t*)smem;      // [128][136] bf16 (pad keeps 16B row align)
        constexpr int TP = 136;
        const int region = col0 >> 10;     // 0=q, 1=k, 2=v (block never straddles)
        if (region < 2) {
            // row-major restage -> coalesced 16B/lane stores
#pragma unroll
            for (int j = 0; j < 4; ++j) {
                int cl = wn * 64 + j * 16 + lm;
                float bv = bias[col0 + cl];
#pragma unroll
                for (int i = 0; i < 4; ++i) {
                    int rl = wm * 64 + i * 16 + g * 4;
#pragma unroll
                    for (int r = 0; r < 4; ++r)
                        tile[(rl + r) * TP + cl] = (bf16_t)(acc[i][j][r] + bv);
                }
            }
            __syncthreads();
            bf16_t* dst = (region == 0) ? (bf16_t*)out0 : (bf16_t*)out1;
            const int colbase = col0 & 1023;
            // full tile = 128 rows x 16 chunks of 8 bf16 = 2048 chunks -> 8 iters x 256 threads
#pragma unroll
            for (int it = 0; it < 8; ++it) {
                int blk = it * 256 + tid;
                int rr = blk >> 4;
                int c8 = (blk & 15) * 8;
                uint4 v = *(const uint4*)&tile[rr * TP + c8];
                *(uint4*)(dst + (size_t)(row0 + rr) * 1024 + colbase + c8) = v;
            }
        } else {
            // v: transposed restage (tileT[col][row]) -> coalesced [B][D][N] stores
#pragma unroll
            for (int j = 0; j < 4; ++j) {
                int cl = wn * 64 + j * 16 + lm;
                float bv = bias[col0 + cl];
#pragma unroll
                for (int i = 0; i < 4; ++i) {
                    int rl = wm * 64 + i * 16 + g * 4;
                    bf16x4 pk;
#pragma unroll
                    for (int r = 0; r < 4; ++r) pk[r] = (bf16_t)(acc[i][j][r] + bv);
                    *(bf16x4*)&tile[cl * TP + rl] = pk;     // 8B, aligned
                }
            }
            __syncthreads();
            bf16_t* vo = (bf16_t*)out2;
            const int bb = row0 >> 11;         // batch (2048 rows per batch; block never straddles)
            const int n0 = row0 & 2047;
            const int dbase = col0 - 2048;
#pragma unroll
            for (int it = 0; it < 8; ++it) {
                int blk = it * 256 + tid;
                int dl = blk >> 4;
                int n8 = (blk & 15) * 8;
                uint4 v = *(const uint4*)&tile[dl * TP + n8];
                *(uint4*)(vo + (size_t)bb * (1024 * 2048) + (size_t)(dbase + dl) * 2048 + (n0 + n8)) = v;
            }
        }
    }
}

// ---------------- local attention ----------------
// 32 queries per block, 8 waves (512 thr). j-SPLIT score phase: wave w owns j-tiles
// t = w, w+8, w+16 and does the FULL K=1024 reduction in-wave via mfma(K_frag, Q_frag)
// with K fragments loaded straight from global (L2-hot). No barriers, no cross-wave
// reduce -> waves run independently and hide each other's load latency.
// Operand convention: both A (K) and B (Q) read contiguous-8 k-slots per lane group;
// identical per-slot permutation on A and B cancels. C: col=lane&15 -> q, row=4g+r -> j.
// PV unchanged (d-split per wave), V pre-transposed Vt[B][D][N].
__global__ __launch_bounds__(512, 1)
void k_attn(const bf16_t* __restrict__ Q, const bf16_t* __restrict__ Km,
            const bf16_t* __restrict__ Vt, bf16_t* __restrict__ AO,
            const int* __restrict__ wptr)
{
    constexpr int Nn = 2048, Dd = 1024;
    constexpr int NJT = 18, JROWS = 288;
    __shared__ bf16_t Qs[32][1032];       //  66048 B
    __shared__ float  St[JROWS][36];      //  41472 B (pitch 36: bank=4r+c -> 2-way, free)
    __shared__ float  red[16][32];        //   2048 B
    __shared__ float  rowrsum[32];        //    128 B  -> 109,696 B total

    const int tid = threadIdx.x;
    const int lane = tid & 63;
    const int w = tid >> 6;               // 0..7
    const int lm = lane & 15, g = lane >> 4;
    // bijective on the 256-block grid: XCD x gets logical tiles [x*32, x*32+32)
    const int lblk = (blockIdx.x & 7) * 32 + (blockIdx.x >> 3);
    const int b = lblk >> 6;
    const int q0 = (lblk & 63) * 32;
    const int win = *wptr;
    int jlo = q0 - win; if (jlo < 0) jlo = 0;

    // stage Q tile (32 x 1024): 4096 8-elem chunks / 512 threads = 8 iters
    {
        const bf16_t* src = Q + ((size_t)(b * Nn + q0)) * Dd;
#pragma unroll
        for (int i = 0; i < 8; ++i) {
            int c = i * 512 + tid;
            int r = c >> 7;
            int ce = (c & 127) * 8;
            *(uint4*)(&Qs[r][ce]) = *(const uint4*)(src + (size_t)r * Dd + ce);
        }
    }
    __syncthreads();

    // ---- score phase: barrier-free, per-wave independent j-tiles ----
    for (int t = w; t < NJT; t += 8) {
        const int j16 = jlo + t * 16;
        int krow = j16 + lm; if (krow > Nn - 1) krow = Nn - 1;   // clamp; masked below
        const bf16_t* kp = Km + ((size_t)(b * Nn + krow)) * Dd + g * 8;
        f32x4 sacc[2];
#pragma unroll
        for (int f = 0; f < 2; ++f) { sacc[f][0]=0.f; sacc[f][1]=0.f; sacc[f][2]=0.f; sacc[f][3]=0.f; }
#pragma unroll 4
        for (int kc = 0; kc < 32; ++kc) {
            U16x8 kf, q0f, q1f;
            kf.q  = *(const uint4*)(kp + kc * 32);
            q0f.q = *(const uint4*)(&Qs[lm][kc * 32 + g * 8]);
            q1f.q = *(const uint4*)(&Qs[16 + lm][kc * 32 + g * 8]);
            sacc[0] = __builtin_amdgcn_mfma_f32_16x16x32_bf16(kf.v, q0f.v, sacc[0], 0, 0, 0);
            sacc[1] = __builtin_amdgcn_mfma_f32_16x16x32_bf16(kf.v, q1f.v, sacc[1], 0, 0, 0);
        }
        // write masked+scaled scores: lane holds S[j16+4g+r][q0 + f*16+lm]
#pragma unroll
        for (int f = 0; f < 2; ++f) {
            int qg = q0 + f * 16 + lm;
#pragma unroll
            for (int r = 0; r < 4; ++r) {
                int jg = j16 + g * 4 + r;
                int dd2 = qg - jg; if (dd2 < 0) dd2 = -dd2;
                bool valid = (jg < Nn) && (dd2 <= win);
                St[t * 16 + g * 4 + r][f * 16 + lm] = valid ? sacc[f][r] * 0.03125f : -3.0e38f;
            }
        }
    }
    __syncthreads();

    // softmax over j per q column; 16 threads per q
    {
        int qq = tid & 31, sub = tid >> 5;   // sub 0..15
        float m = -3.0e38f;
        for (int j = sub; j < JROWS; j += 16) m = fmaxf(m, St[j][qq]);
        red[sub][qq] = m;
        __syncthreads();
        float mm = red[0][qq];
#pragma unroll
        for (int s2 = 1; s2 < 16; ++s2) mm = fmaxf(mm, red[s2][qq]);
        __syncthreads();   // all reads of red done before re-use
        float sum = 0.f;
        for (int j = sub; j < JROWS; j += 16) {
            float p = __expf(St[j][qq] - mm);
            St[j][qq] = p;
            sum += p;
        }
        red[sub][qq] = sum;
        __syncthreads();
        float ss = 0.f;
#pragma unroll
        for (int s2 = 0; s2 < 16; ++s2) ss += red[s2][qq];
        if (sub == 0) rowrsum[qq] = 1.f / ss;
    }
    __syncthreads();

    // PV: wave w owns output d-chunk [w*128, w*128+128)
    f32x4 oacc[2][8];
#pragma unroll
    for (int f = 0; f < 2; ++f)
#pragma unroll
        for (int nf = 0; nf < 8; ++nf) { oacc[f][nf][0]=0.f; oacc[f][nf][1]=0.f; oacc[f][nf][2]=0.f; oacc[f][nf][3]=0.f; }

    const bf16_t* vbase = Vt + (size_t)b * Dd * Nn;
    for (int ks = 0; ks < 9; ++ks) {   // 288/32
        int jb = ks * 32;
        bf16x8 pf[2];
#pragma unroll
        for (int f = 0; f < 2; ++f) {
            int qq = f * 16 + lm;
            bf16x8 v;
#pragma unroll
            for (int h = 0; h < 2; ++h)
#pragma unroll
                for (int i2 = 0; i2 < 4; ++i2)
                    v[h * 4 + i2] = (bf16_t)St[jb + h * 16 + g * 4 + i2][qq];
            pf[f] = v;
        }
        U16x8 bl[8];
        int j0g = jlo + jb + g * 4;      if (j0g > Nn - 4) j0g = Nn - 4;   // clamped lanes have p=0
        int j1g = jlo + jb + 16 + g * 4; if (j1g > Nn - 4) j1g = Nn - 4;
#pragma unroll
        for (int nf = 0; nf < 8; ++nf) {
            int d = w * 128 + nf * 16 + lm;
            const bf16_t* vp = vbase + (size_t)d * Nn;
            bl[nf].u[0] = *(const uint2*)(vp + j0g);
            bl[nf].u[1] = *(const uint2*)(vp + j1g);
        }
#pragma unroll
        for (int nf = 0; nf < 8; ++nf)
#pragma unroll
            for (int f = 0; f < 2; ++f)
                oacc[f][nf] = __builtin_amdgcn_mfma_f32_16x16x32_bf16(pf[f], bl[nf].v, oacc[f][nf], 0, 0, 0);
    }

    // epilogue: scale by 1/sum, write bf16
#pragma unroll
    for (int f = 0; f < 2; ++f) {
#pragma unroll
        for (int r = 0; r < 4; ++r) {
            int qq = f * 16 + g * 4 + r;
            float rs = rowrsum[qq];
            size_t rowg = (size_t)(b * Nn + q0 + qq) * Dd;
#pragma unroll
            for (int nf = 0; nf < 8; ++nf) {
                int d = w * 128 + nf * 16 + lm;
                AO[rowg + d] = (bf16_t)(oacc[f][nf][r] * rs);
            }
        }
    }
}

extern "C" void kernel_launch(void* const* d_in, const int* in_sizes, int n_in,
                              void* d_out, int out_size, void* d_ws, size_t ws_size,
                              hipStream_t stream)
{
    (void)in_sizes; (void)n_in; (void)out_size; (void)ws_size;
    const float* x      = (const float*)d_in[0];
    const float* w_qkv  = (const float*)d_in[1];
    const float* b_qkv  = (const float*)d_in[2];
    const float* w_proj = (const float*)d_in[3];
    const float* b_proj = (const float*)d_in[4];
    const int*   wsz    = (const int*)d_in[5];
    float* out = (float*)d_out;

    constexpr int Bb = 4, Nn = 2048, Dd = 1024;
    constexpr int M = Bb * Nn, N3 = 3 * Dd;

    char* p = (char*)d_ws;
    bf16_t* xb     = (bf16_t*)p; p += (size_t)M * Dd * 2;
    bf16_t* wqkvT  = (bf16_t*)p; p += (size_t)N3 * Dd * 2;
    bf16_t* wprojT = (bf16_t*)p; p += (size_t)Dd * Dd * 2;
    bf16_t* qb     = (bf16_t*)p; p += (size_t)M * Dd * 2;
    bf16_t* kb     = (bf16_t*)p; p += (size_t)M * Dd * 2;
    bf16_t* vtb    = (bf16_t*)p; p += (size_t)M * Dd * 2;
    bf16_t* ao     = xb;  // alias: xb dead after QKV GEMM

    k_convert_bf16<<<2048, 256, 0, stream>>>(x, xb, M * Dd / 4);
    k_transpose_bf16<<<dim3(N3 / 32, Dd / 32), 256, 0, stream>>>(w_qkv, wqkvT, Dd, N3);
    k_transpose_bf16<<<dim3(Dd / 32, Dd / 32), 256, 0, stream>>>(w_proj, wprojT, Dd, Dd);
    gemm_bt<0><<<1536, 256, 0, stream>>>(xb, wqkvT, b_qkv, qb, kb, vtb, 24, N3, Dd);
    k_attn<<<Bb * (Nn / 32), 512, 0, stream>>>(qb, kb, vtb, ao, wsz);
    gemm_bt<1><<<512, 256, 0, stream>>>(ao, wprojT, b_proj, out, nullptr, nullptr, 8, Dd, Dd);
}